// Round 13
// baseline (2071.760 us; speedup 1.0000x reference)
//
#include <hip/hip_runtime.h>
#include <hip/hip_bf16.h>

#define NB  16
#define NN  16384
#define NC  256
#define NPP 128
#define NSS 16

#define FBLK 8    // fps blocks per batch
#define FTH  512  // fps threads per block (8 waves)
#define FPT  4    // points per thread = 16384/(8*512)

// ---------------- weight transpose + slot zeroing (one-shot, tiny) --------
__global__ __launch_bounds__(256) void transpose_kernel(
    const float* __restrict__ W1, const float* __restrict__ W2,
    const float* __restrict__ W3, const float* __restrict__ Wm,
    float* __restrict__ W1T, float* __restrict__ W2T,
    float* __restrict__ W3T, float* __restrict__ WmT,
    unsigned long long* __restrict__ slots) {
  int i = blockIdx.x * 256 + threadIdx.x;
  if (i < 2048) slots[i] = 0ull;   // 16 batches x 8 blocks x 2 parity x 8 u64
  if (i < 128 * 259) { int o = i / 259, c = i - o * 259; W1T[c * 128 + o] = W1[i]; }
  if (i < 128 * 128) {
    int o = i >> 7, c = i & 127;
    W2T[c * 128 + o] = W2[i];
    W3T[c * 128 + o] = W3[i];
    WmT[c * 128 + o] = Wm[i];
    WmT[16384 + c * 128 + o] = Wm[16384 + i];
  }
}

// ---------------- FPS: 8 blocks per batch, flag-sync exchange -------------
// Exact numpy semantics: d = ((dx*dx + dy*dy) + dz*dz), per-op rounding,
// argmax tie-break = lowest index. Packed candidate (ONE u64 = payload+tag):
//   pk = f32bits(val)<<32 | (16383-idx)<<7 | it
// val>=0 so bits are monotone; larger (16383-idx) = smaller idx; tag bits
// equal within an iteration so ordering is unaffected.
// r2-r12 lesson: 16384 pts on one CU is phase-sum bound (~1.8us/iter
// invariant under all layouts). Here: 2048 pts/block, 4/thread -> pure
// register state (16 floats), j-loop ~200cyc/CU. Cross-block combine via
// device-scope tagged slots (zeroed every call by transpose_kernel;
// parity double-buffered; barrier chain prevents overwrite-before-read).
// All 128 blocks co-resident (1024 waves << 8192 capacity) -> spin is safe.
__global__ __attribute__((amdgpu_flat_work_group_size(FTH, FTH)))
void fps_kernel(
    const float* __restrict__ xyz,
    unsigned long long* __restrict__ slots,
    float* __restrict__ centers, float* __restrict__ out_xyz,
    float* __restrict__ out_indf) {
  int bb = blockIdx.x;
  int b = bb >> 3, myblk = bb & 7;
  const float* px = xyz + (size_t)b * (NN * 3);
  int t = threadIdx.x;
  int base = myblk << 11;                      // * 2048
  float X[FPT], Y[FPT], Z[FPT], MD[FPT];
#pragma unroll
  for (int j = 0; j < FPT; ++j) {
    int n = base + (j << 9) + t;
    float x = px[n * 3 + 0];
    float y = px[n * 3 + 1];
    float z = px[n * 3 + 2];
    asm volatile("" : "+v"(x), "+v"(y), "+v"(z));
    X[j] = x; Y[j] = y; Z[j] = z;
    MD[j] = 1e10f;
  }
  __shared__ unsigned long long cand[2][8];
  __shared__ float4 hist[NPP];
  float cx = px[0], cy = px[1], cz = px[2];
  if (t == 0 && myblk == 0) hist[0] = make_float4(cx, cy, cz, 0.0f);
  for (int it = 1; it < NPP; ++it) {
    float bv = -1.0f;
    int bi = 0;
#pragma unroll
    for (int j = 0; j < FPT; ++j) {
      float dx = __fsub_rn(X[j], cx);
      float dy = __fsub_rn(Y[j], cy);
      float dz = __fsub_rn(Z[j], cz);
      float d  = __fadd_rn(__fadd_rn(__fmul_rn(dx, dx), __fmul_rn(dy, dy)),
                           __fmul_rn(dz, dz));
      float m = fminf(MD[j], d);
      MD[j] = m;
      if (m > bv) { bv = m; bi = base + (j << 9) + t; }  // first occurrence
    }
    unsigned long long pk =
        (((unsigned long long)__float_as_uint(bv)) << 32) |
        ((unsigned long long)(16383 - bi) << 7) |
        (unsigned long long)it;
    // ---- wave64 max-reduce: 4x DPP row_ror + swizzle xor16 + shfl xor32 --
#define STEP_ROR(N)                                                         \
    {                                                                       \
      unsigned lo = (unsigned)pk, hi = (unsigned)(pk >> 32);                \
      lo = (unsigned)__builtin_amdgcn_mov_dpp((int)lo, 0x120 | N, 0xF, 0xF, true); \
      hi = (unsigned)__builtin_amdgcn_mov_dpp((int)hi, 0x120 | N, 0xF, 0xF, true); \
      unsigned long long o = ((unsigned long long)hi << 32) | lo;           \
      if (o > pk) pk = o;                                                   \
    }
    STEP_ROR(1) STEP_ROR(2) STEP_ROR(4) STEP_ROR(8)
    {  // lane ^ 16 within 32-lane halves (ds_swizzle BitMode 0x401F)
      unsigned lo = (unsigned)pk, hi = (unsigned)(pk >> 32);
      lo = (unsigned)__builtin_amdgcn_ds_swizzle((int)lo, 0x401F);
      hi = (unsigned)__builtin_amdgcn_ds_swizzle((int)hi, 0x401F);
      unsigned long long o = ((unsigned long long)hi << 32) | lo;
      if (o > pk) pk = o;
    }
    {  // lane ^ 32
      unsigned long long o = __shfl_xor(pk, 32, 64);
      if (o > pk) pk = o;
    }
    int p = it & 1;
    if ((t & 63) == 0) cand[p][t >> 6] = pk;
    __syncthreads();
    // ---- 8-candidate block combine: lanes hold cand[t&7]; ror 1,2,4
    //      covers any 8 consecutive lanes mod 16 -> all residues mod 8.
    pk = cand[p][t & 7];
    STEP_ROR(1) STEP_ROR(2) STEP_ROR(4)
#undef STEP_ROR
    // ---- post block winner (single-u64 tagged slot, 64B stride) ----
    if (t == 0) {
      __hip_atomic_store(slots + (unsigned)((((b << 3) | myblk) << 1) | p) * 8,
                         pk, __ATOMIC_RELEASE, __HIP_MEMORY_SCOPE_AGENT);
    }
    // ---- every wave: lanes 0-7 spin on the 8 slots, combine ----
    unsigned long long opk = 0;
    int lane = t & 63;
    if (lane < 8) {
      const unsigned long long* so =
          slots + (unsigned)((((b << 3) | lane) << 1) | p) * 8;
      do {
        opk = __hip_atomic_load(so, __ATOMIC_ACQUIRE, __HIP_MEMORY_SCOPE_AGENT);
      } while ((opk & 127ull) != (unsigned long long)it);
      { unsigned long long o = __shfl_xor(opk, 1, 64); if (o > opk) opk = o; }
      { unsigned long long o = __shfl_xor(opk, 2, 64); if (o > opk) opk = o; }
      { unsigned long long o = __shfl_xor(opk, 4, 64); if (o > opk) opk = o; }
    }
    int win;
    {
      int w = 16383 - (int)((opk >> 7) & 16383ull);
      win = __builtin_amdgcn_readfirstlane(w);   // lane 0 has combined value
    }
    cx = px[win * 3 + 0];                        // uniform scalar loads (L2)
    cy = px[win * 3 + 1];
    cz = px[win * 3 + 2];
    if (t == 0 && myblk == 0) hist[it] = make_float4(cx, cy, cz, (float)win);
  }
  if (myblk == 0) {
    __syncthreads();
    if (t < NPP) {                               // one-shot output flush
      float4 h = hist[t];
      centers[(b * NPP + t) * 3 + 0] = h.x;
      centers[(b * NPP + t) * 3 + 1] = h.y;
      centers[(b * NPP + t) * 3 + 2] = h.z;
      out_xyz[(b * NPP + t) * 3 + 0] = h.x;
      out_xyz[(b * NPP + t) * 3 + 1] = h.y;
      out_xyz[(b * NPP + t) * 3 + 2] = h.z;
      out_indf[b * NPP + t] = h.w;
    }
  }
}

// ---------------- ball query: one wave per (b, center) ----------------
__global__ __launch_bounds__(64) void ballq_kernel(
    const float* __restrict__ xyz, const float* __restrict__ centers,
    int* __restrict__ bidx) {
  int bs = blockIdx.x;  // b*128 + s
  int b = bs >> 7;
  int lane = threadIdx.x;
  const float* px = xyz + (size_t)b * (NN * 3);
  float cx = centers[bs * 3 + 0];
  float cy = centers[bs * 3 + 1];
  float cz = centers[bs * 3 + 2];
  __shared__ int coll[NSS];
  const float rr = 0.09f;  // f32(0.09): identical membership to f64 compare
  int have = 0;
  for (int c0 = 0; c0 < NN; c0 += 64) {
    int n = c0 + lane;
    float dx = __fsub_rn(px[n * 3 + 0], cx);
    float dy = __fsub_rn(px[n * 3 + 1], cy);
    float dz = __fsub_rn(px[n * 3 + 2], cz);
    float d2 = __fadd_rn(__fadd_rn(__fmul_rn(dx, dx), __fmul_rn(dy, dy)),
                         __fmul_rn(dz, dz));
    bool in = d2 < rr;
    unsigned long long m = __ballot(in);
    if (in) {
      int pos = have + __popcll(m & ((1ull << lane) - 1ull));
      if (pos < NSS) coll[pos] = n;
    }
    have += __popcll(m);
    if (have >= NSS) break;
  }
  __syncthreads();
  int first = coll[0];
  if (lane < NSS) bidx[bs * NSS + lane] = (lane < have) ? coll[lane] : first;
}

// ---------------- grouped MLP: 128 thr, 4 outputs x 4 k per thread -------
__device__ __forceinline__ float4 bnrelu4(float4 a, float s, float b) {
  float4 r;
  r.x = fmaxf(fmaf(a.x, s, b), 0.f);
  r.y = fmaxf(fmaf(a.y, s, b), 0.f);
  r.z = fmaxf(fmaf(a.z, s, b), 0.f);
  r.w = fmaxf(fmaf(a.w, s, b), 0.f);
  return r;
}

__device__ __forceinline__ void layer4(const float (*in)[20], int cin,
                                       const float* __restrict__ WT,
                                       const float* __restrict__ sc,
                                       const float* __restrict__ bi,
                                       int o4, int k0,
                                       float4& r0, float4& r1,
                                       float4& r2, float4& r3) {
  float4 a0 = {0.f, 0.f, 0.f, 0.f}, a1 = a0, a2 = a0, a3 = a0;
  for (int c = 0; c < cin; ++c) {
    float4 w  = *(const float4*)(WT + c * 128 + o4);
    float4 gv = *(const float4*)(&in[c][k0]);
    a0.x = fmaf(w.x, gv.x, a0.x); a0.y = fmaf(w.x, gv.y, a0.y);
    a0.z = fmaf(w.x, gv.z, a0.z); a0.w = fmaf(w.x, gv.w, a0.w);
    a1.x = fmaf(w.y, gv.x, a1.x); a1.y = fmaf(w.y, gv.y, a1.y);
    a1.z = fmaf(w.y, gv.z, a1.z); a1.w = fmaf(w.y, gv.w, a1.w);
    a2.x = fmaf(w.z, gv.x, a2.x); a2.y = fmaf(w.z, gv.y, a2.y);
    a2.z = fmaf(w.z, gv.z, a2.z); a2.w = fmaf(w.z, gv.w, a2.w);
    a3.x = fmaf(w.w, gv.x, a3.x); a3.y = fmaf(w.w, gv.y, a3.y);
    a3.z = fmaf(w.w, gv.z, a3.z); a3.w = fmaf(w.w, gv.w, a3.w);
  }
  r0 = bnrelu4(a0, sc[o4 + 0], bi[o4 + 0]);
  r1 = bnrelu4(a1, sc[o4 + 1], bi[o4 + 1]);
  r2 = bnrelu4(a2, sc[o4 + 2], bi[o4 + 2]);
  r3 = bnrelu4(a3, sc[o4 + 3], bi[o4 + 3]);
}

__global__ __launch_bounds__(128) void mlp_kernel(
    const float* __restrict__ xyz, const float* __restrict__ feats,
    const float* __restrict__ centers, const int* __restrict__ bidx,
    const float* __restrict__ W1T, const float* __restrict__ W2T,
    const float* __restrict__ W3T, const float* __restrict__ sa_sc,
    const float* __restrict__ sa_bi, float* __restrict__ feat0) {
  int bs = blockIdx.x;
  int b = bs >> 7;
  int s = bs & 127;
  int tid = threadIdx.x;
  __shared__ __align__(16) float g[259][20];   // 20720 B
  __shared__ __align__(16) float h1[128][20];  // 10240 B
  float (*h2)[20] = (float (*)[20]) & g[0][0]; // alias: g dead after layer1
  __shared__ int kidx[NSS];
  __shared__ float ctr[3];
  if (tid < NSS) kidx[tid] = bidx[bs * NSS + tid];
  if (tid < 3) ctr[tid] = centers[bs * 3 + tid];
  __syncthreads();
  const float* px = xyz + (size_t)b * (NN * 3);
  if (tid < NSS) {
    int n = kidx[tid];
    g[0][tid] = __fdiv_rn(__fsub_rn(px[n * 3 + 0], ctr[0]), 0.3f);
    g[1][tid] = __fdiv_rn(__fsub_rn(px[n * 3 + 1], ctr[1]), 0.3f);
    g[2][tid] = __fdiv_rn(__fsub_rn(px[n * 3 + 2], ctr[2]), 0.3f);
  }
#pragma unroll
  for (int cc = 0; cc < 2; ++cc) {
    int c = tid + cc * 128;
    const float* row = feats + ((size_t)b * NC + c) * NN;
#pragma unroll
    for (int k = 0; k < NSS; ++k) g[3 + c][k] = row[kidx[k]];
  }
  __syncthreads();
  int o4 = (tid & 31) * 4;
  int k0 = (tid >> 5) * 4;   // 0,4,8,12
  float4 r0, r1, r2, r3;
  layer4(g, 259, W1T, sa_sc, sa_bi, o4, k0, r0, r1, r2, r3);
  *(float4*)&h1[o4 + 0][k0] = r0;
  *(float4*)&h1[o4 + 1][k0] = r1;
  *(float4*)&h1[o4 + 2][k0] = r2;
  *(float4*)&h1[o4 + 3][k0] = r3;
  __syncthreads();
  layer4(h1, 128, W2T, sa_sc + 128, sa_bi + 128, o4, k0, r0, r1, r2, r3);
  __syncthreads();
  *(float4*)&h2[o4 + 0][k0] = r0;
  *(float4*)&h2[o4 + 1][k0] = r1;
  *(float4*)&h2[o4 + 2][k0] = r2;
  *(float4*)&h2[o4 + 3][k0] = r3;
  __syncthreads();
  layer4(h2, 128, W3T, sa_sc + 256, sa_bi + 256, o4, k0, r0, r1, r2, r3);
  float m0 = fmaxf(fmaxf(r0.x, r0.y), fmaxf(r0.z, r0.w));
  float m1 = fmaxf(fmaxf(r1.x, r1.y), fmaxf(r1.z, r1.w));
  float m2 = fmaxf(fmaxf(r2.x, r2.y), fmaxf(r2.z, r2.w));
  float m3 = fmaxf(fmaxf(r3.x, r3.y), fmaxf(r3.z, r3.w));
  int kg = tid >> 5;
  h1[o4 + 0][kg] = m0;
  h1[o4 + 1][kg] = m1;
  h1[o4 + 2][kg] = m2;
  h1[o4 + 3][kg] = m3;
  __syncthreads();
  if (tid < 128) {
    float m = fmaxf(fmaxf(h1[tid][0], h1[tid][1]), fmaxf(h1[tid][2], h1[tid][3]));
    feat0[((size_t)b * 128 + tid) * 128 + s] = m;
  }
}

// ---------------- FC heads: (x@Wm + bm)*scale + bias, relu, x2 ----------------
__global__ __launch_bounds__(256) void head_kernel(
    const float* __restrict__ feat0, const float* __restrict__ WmT,
    const float* __restrict__ bm, const float* __restrict__ msc,
    const float* __restrict__ mbi, float* __restrict__ out_feat) {
  int blk = blockIdx.x;
  int b = blk >> 2;
  int sbase = (blk & 3) * 32;
  int tid = threadIdx.x;
  __shared__ float fa[128][36];
  __shared__ float fb[128][36];
  {
    int sj = tid & 31, c0 = tid >> 5;
    for (int c = c0; c < 128; c += 8)
      fa[c][sj] = feat0[((size_t)b * 128 + c) * 128 + sbase + sj];
  }
  __syncthreads();
  int o2 = (tid & 63) * 2, s0 = (tid >> 6) * 8;
  float a0[8], a1[8];
#pragma unroll
  for (int j = 0; j < 8; ++j) { a0[j] = 0.f; a1[j] = 0.f; }
  for (int c = 0; c < 128; ++c) {
    float2 w = *(const float2*)&WmT[c * 128 + o2];
    float4 f0 = *(const float4*)&fa[c][s0];
    float4 f1 = *(const float4*)&fa[c][s0 + 4];
    a0[0] = fmaf(w.x, f0.x, a0[0]); a0[1] = fmaf(w.x, f0.y, a0[1]);
    a0[2] = fmaf(w.x, f0.z, a0[2]); a0[3] = fmaf(w.x, f0.w, a0[3]);
    a0[4] = fmaf(w.x, f1.x, a0[4]); a0[5] = fmaf(w.x, f1.y, a0[5]);
    a0[6] = fmaf(w.x, f1.z, a0[6]); a0[7] = fmaf(w.x, f1.w, a0[7]);
    a1[0] = fmaf(w.y, f0.x, a1[0]); a1[1] = fmaf(w.y, f0.y, a1[1]);
    a1[2] = fmaf(w.y, f0.z, a1[2]); a1[3] = fmaf(w.y, f0.w, a1[3]);
    a1[4] = fmaf(w.y, f1.x, a1[4]); a1[5] = fmaf(w.y, f1.y, a1[5]);
    a1[6] = fmaf(w.y, f1.z, a1[6]); a1[7] = fmaf(w.y, f1.w, a1[7]);
  }
  {
    float c0 = bm[o2], c1 = bm[o2 + 1];
    float t0 = msc[o2], t1 = msc[o2 + 1];
    float q0 = mbi[o2], q1 = mbi[o2 + 1];
#pragma unroll
    for (int j = 0; j < 8; ++j) {
      fb[o2][s0 + j]     = fmaxf(fmaf(a0[j] + c0, t0, q0), 0.f);
      fb[o2 + 1][s0 + j] = fmaxf(fmaf(a1[j] + c1, t1, q1), 0.f);
    }
  }
  __syncthreads();
#pragma unroll
  for (int j = 0; j < 8; ++j) { a0[j] = 0.f; a1[j] = 0.f; }
  for (int c = 0; c < 128; ++c) {
    float2 w = *(const float2*)&WmT[16384 + c * 128 + o2];
    float4 f0 = *(const float4*)&fb[c][s0];
    float4 f1 = *(const float4*)&fb[c][s0 + 4];
    a0[0] = fmaf(w.x, f0.x, a0[0]); a0[1] = fmaf(w.x, f0.y, a0[1]);
    a0[2] = fmaf(w.x, f0.z, a0[2]); a0[3] = fmaf(w.x, f0.w, a0[3]);
    a0[4] = fmaf(w.x, f1.x, a0[4]); a0[5] = fmaf(w.x, f1.y, a0[5]);
    a0[6] = fmaf(w.x, f1.z, a0[6]); a0[7] = fmaf(w.x, f1.w, a0[7]);
    a1[0] = fmaf(w.y, f0.x, a1[0]); a1[1] = fmaf(w.y, f0.y, a1[1]);
    a1[2] = fmaf(w.y, f0.z, a1[2]); a1[3] = fmaf(w.y, f0.w, a1[3]);
    a1[4] = fmaf(w.y, f1.x, a1[4]); a1[5] = fmaf(w.y, f1.y, a1[5]);
    a1[6] = fmaf(w.y, f1.z, a1[6]); a1[7] = fmaf(w.y, f1.w, a1[7]);
  }
  {
    float c0 = bm[128 + o2], c1 = bm[128 + o2 + 1];
    float t0 = msc[128 + o2], t1 = msc[128 + o2 + 1];
    float q0 = mbi[128 + o2], q1 = mbi[128 + o2 + 1];
    float4 v0a, v0b, v1a, v1b;
    v0a.x = fmaxf(fmaf(a0[0] + c0, t0, q0), 0.f);
    v0a.y = fmaxf(fmaf(a0[1] + c0, t0, q0), 0.f);
    v0a.z = fmaxf(fmaf(a0[2] + c0, t0, q0), 0.f);
    v0a.w = fmaxf(fmaf(a0[3] + c0, t0, q0), 0.f);
    v0b.x = fmaxf(fmaf(a0[4] + c0, t0, q0), 0.f);
    v0b.y = fmaxf(fmaf(a0[5] + c0, t0, q0), 0.f);
    v0b.z = fmaxf(fmaf(a0[6] + c0, t0, q0), 0.f);
    v0b.w = fmaxf(fmaf(a0[7] + c0, t0, q0), 0.f);
    v1a.x = fmaxf(fmaf(a1[0] + c1, t1, q1), 0.f);
    v1a.y = fmaxf(fmaf(a1[1] + c1, t1, q1), 0.f);
    v1a.z = fmaxf(fmaf(a1[2] + c1, t1, q1), 0.f);
    v1a.w = fmaxf(fmaf(a1[3] + c1, t1, q1), 0.f);
    v1b.x = fmaxf(fmaf(a1[4] + c1, t1, q1), 0.f);
    v1b.y = fmaxf(fmaf(a1[5] + c1, t1, q1), 0.f);
    v1b.z = fmaxf(fmaf(a1[6] + c1, t1, q1), 0.f);
    v1b.w = fmaxf(fmaf(a1[7] + c1, t1, q1), 0.f);
    float* p0 = &out_feat[((size_t)b * 128 + o2) * 128 + sbase + s0];
    float* p1 = &out_feat[((size_t)b * 128 + o2 + 1) * 128 + sbase + s0];
    *(float4*)p0 = v0a;
    *(float4*)(p0 + 4) = v0b;
    *(float4*)p1 = v1a;
    *(float4*)(p1 + 4) = v1b;
  }
}

extern "C" void kernel_launch(void* const* d_in, const int* in_sizes, int n_in,
                              void* d_out, int out_size, void* d_ws, size_t ws_size,
                              hipStream_t stream) {
  const float* vote_xyz  = (const float*)d_in[0];
  const float* vote_feat = (const float*)d_in[1];
  const float* W1   = (const float*)d_in[2];
  const float* W2   = (const float*)d_in[3];
  const float* W3   = (const float*)d_in[4];
  const float* sasc = (const float*)d_in[5];
  const float* sabi = (const float*)d_in[6];
  const float* Wm   = (const float*)d_in[7];
  const float* bm   = (const float*)d_in[8];
  const float* msc  = (const float*)d_in[9];
  const float* mbi  = (const float*)d_in[10];

  float* out = (float*)d_out;
  float* out_xyz  = out;                    // B*NP*3   = 6144
  float* out_feat = out + 6144;             // B*128*NP = 262144
  float* out_indf = out + 6144 + 262144;    // B*NP     = 2048

  char* ws = (char*)d_ws;
  unsigned long long* slots = (unsigned long long*)(ws + 0);  // 16 KB
  float* centers = (float*)(ws + 16384);    // 24576 B -> end 40960
  int*   bidx    = (int*)(ws + 40960);      // 131072 B -> end 172032
  float* W1T     = (float*)(ws + 172032);   // 132608 B -> end 304640
  float* W2T     = (float*)(ws + 304640);   // 65536 B -> end 370176
  float* W3T     = (float*)(ws + 370176);   // 65536 B -> end 435712
  float* WmT     = (float*)(ws + 435712);   // 131072 B -> end 566784
  float* feat0   = (float*)(ws + 566784);   // 1 MB -> end 1615360

  hipLaunchKernelGGL(transpose_kernel, dim3(130), dim3(256), 0, stream,
                     W1, W2, W3, Wm, W1T, W2T, W3T, WmT, slots);
  hipLaunchKernelGGL(fps_kernel, dim3(NB * FBLK), dim3(FTH), 0, stream,
                     vote_xyz, slots, centers, out_xyz, out_indf);
  hipLaunchKernelGGL(ballq_kernel, dim3(NB * NPP), dim3(64), 0, stream,
                     vote_xyz, centers, bidx);
  hipLaunchKernelGGL(mlp_kernel, dim3(NB * NPP), dim3(128), 0, stream,
                     vote_xyz, vote_feat, centers, bidx, W1T, W2T, W3T,
                     sasc, sabi, feat0);
  hipLaunchKernelGGL(head_kernel, dim3(NB * 4), dim3(256), 0, stream,
                     feat0, WmT, bm, msc, mbi, out_feat);
}

// Round 15
// 355.688 us; speedup vs baseline: 5.8247x; 5.8247x over previous
//
#include <hip/hip_runtime.h>
#include <hip/hip_bf16.h>

#define NB  16
#define NN  16384
#define NC  256
#define NPP 128
#define NSS 16

#define FTH 1024  // fps threads per block (16 waves = 4 waves/SIMD)

// ---------------- weight transpose (one-shot, tiny) ----------------
__global__ __launch_bounds__(256) void transpose_kernel(
    const float* __restrict__ W1, const float* __restrict__ W2,
    const float* __restrict__ W3, const float* __restrict__ Wm,
    float* __restrict__ W1T, float* __restrict__ W2T,
    float* __restrict__ W3T, float* __restrict__ WmT) {
  int i = blockIdx.x * 256 + threadIdx.x;
  if (i < 128 * 259) { int o = i / 259, c = i - o * 259; W1T[c * 128 + o] = W1[i]; }
  if (i < 128 * 128) {
    int o = i >> 7, c = i & 127;
    W2T[c * 128 + o] = W2[i];
    W3T[c * 128 + o] = W3[i];
    WmT[c * 128 + o] = Wm[i];
    WmT[16384 + c * 128 + o] = Wm[16384 + i];
  }
}

// ---------------- FPS: one block per batch (r10 layout, 16-wave combine) --
// Exact numpy semantics: d = ((dx*dx + dy*dy) + dz*dz), per-op rounding,
// argmax tie-break = lowest index via packed u64 max: pk = valbits<<32 | ~idx.
// 16 WAVES -> cand[2][16], combine over t&15 with ROR 1,2,4,8 (r14 bug:
// 8-slot combine dropped waves 8-15 -> half-subsample FPS -> wrong indices).
// Floor note (r2-r13): 10 structural variants all 1.73-1.94 us/iter; the
// sequential-argmax phase-sum is the single-block floor; multi-block
// exchange is 8x WORSE (cross-XCD coherence, r13).
__global__ __attribute__((amdgpu_flat_work_group_size(1024, 1024)))
void fps_kernel(
    const float* __restrict__ xyz,
    float* __restrict__ centers, float* __restrict__ out_xyz,
    float* __restrict__ out_indf) {
  int b = blockIdx.x;
  const float* px = xyz + (size_t)b * (NN * 3);
  int t = threadIdx.x;
  __shared__ float2 sxy[NN / 2];               // 64 KB: points 8192..16383
  __shared__ unsigned long long cand[2][16];
  __shared__ float4 hist[NPP];                 // per-iter (cx,cy,cz,idx)
  float Xr[8], Yr[8], Zr[16], MD[16];
#pragma unroll
  for (int j = 0; j < 16; ++j) {
    int n = t + (j << 10);
    float x = px[n * 3 + 0];
    float y = px[n * 3 + 1];
    float z = px[n * 3 + 2];
    asm volatile("" : "+v"(z));                // z: reg-resident, no re-load
    if (j < 8) {
      asm volatile("" : "+v"(x), "+v"(y));     // first 8 pts: xy in regs
      Xr[j] = x; Yr[j] = y;
    } else {
      sxy[n - 8192] = make_float2(x, y);       // last 8 pts: xy in LDS
    }
    Zr[j] = z;
    MD[j] = 1e10f;
  }
  float cx = px[0], cy = px[1], cz = px[2];
  if (t == 0) hist[0] = make_float4(cx, cy, cz, 0.0f);
  __syncthreads();
  for (int it = 1; it < NPP; ++it) {
    float bv = -1.0f;
    int bi = 0;
#pragma unroll
    for (int j = 0; j < 8; ++j) {              // register points
      float dx = __fsub_rn(Xr[j], cx);
      float dy = __fsub_rn(Yr[j], cy);
      float dz = __fsub_rn(Zr[j], cz);
      float d  = __fadd_rn(__fadd_rn(__fmul_rn(dx, dx), __fmul_rn(dy, dy)),
                           __fmul_rn(dz, dz));
      float m = fminf(MD[j], d);
      MD[j] = m;
      if (m > bv) { bv = m; bi = t + (j << 10); }
    }
#pragma unroll
    for (int j = 8; j < 16; ++j) {             // LDS points
      float2 v = sxy[t + ((j - 8) << 10)];
      float dx = __fsub_rn(v.x, cx);
      float dy = __fsub_rn(v.y, cy);
      float dz = __fsub_rn(Zr[j], cz);
      float d  = __fadd_rn(__fadd_rn(__fmul_rn(dx, dx), __fmul_rn(dy, dy)),
                           __fmul_rn(dz, dz));
      float m = fminf(MD[j], d);
      MD[j] = m;
      if (m > bv) { bv = m; bi = t + (j << 10); }
    }
    unsigned long long pk =
        (((unsigned long long)__float_as_uint(bv)) << 32) |
        (unsigned long long)(~(unsigned)bi);
    // ---- wave64 max-reduce: 4x DPP row_ror + swizzle xor16 + shfl xor32 --
#define STEP_ROR(N)                                                         \
    {                                                                       \
      unsigned lo = (unsigned)pk, hi = (unsigned)(pk >> 32);                \
      lo = (unsigned)__builtin_amdgcn_mov_dpp((int)lo, 0x120 | N, 0xF, 0xF, true); \
      hi = (unsigned)__builtin_amdgcn_mov_dpp((int)hi, 0x120 | N, 0xF, 0xF, true); \
      unsigned long long o = ((unsigned long long)hi << 32) | lo;           \
      if (o > pk) pk = o;                                                   \
    }
    STEP_ROR(1) STEP_ROR(2) STEP_ROR(4) STEP_ROR(8)
    {  // lane ^ 16 within 32-lane halves (ds_swizzle BitMode 0x401F)
      unsigned lo = (unsigned)pk, hi = (unsigned)(pk >> 32);
      lo = (unsigned)__builtin_amdgcn_ds_swizzle((int)lo, 0x401F);
      hi = (unsigned)__builtin_amdgcn_ds_swizzle((int)hi, 0x401F);
      unsigned long long o = ((unsigned long long)hi << 32) | lo;
      if (o > pk) pk = o;
    }
    {  // lane ^ 32
      unsigned long long o = __shfl_xor(pk, 32, 64);
      if (o > pk) pk = o;
    }
    int p = it & 1;
    if ((t & 63) == 0) cand[p][t >> 6] = pk;   // 16 waves -> slots 0..15
    __syncthreads();
    // ---- 16-candidate combine: broadcast read + 4 DPP row_ror steps ----
    pk = cand[p][t & 15];
    STEP_ROR(1) STEP_ROR(2) STEP_ROR(4) STEP_ROR(8)
#undef STEP_ROR
    int win = (int)(~(unsigned)(pk & 0xFFFFFFFFull));
    win = __builtin_amdgcn_readfirstlane(win);
    cx = px[win * 3 + 0];                      // uniform scalar loads (L2)
    cy = px[win * 3 + 1];
    cz = px[win * 3 + 2];
    if (t == 0) hist[it] = make_float4(cx, cy, cz, (float)win);
  }
  __syncthreads();
  if (t < NPP) {                               // one-shot output flush
    float4 h = hist[t];
    centers[(b * NPP + t) * 3 + 0] = h.x;
    centers[(b * NPP + t) * 3 + 1] = h.y;
    centers[(b * NPP + t) * 3 + 2] = h.z;
    out_xyz[(b * NPP + t) * 3 + 0] = h.x;
    out_xyz[(b * NPP + t) * 3 + 1] = h.y;
    out_xyz[(b * NPP + t) * 3 + 2] = h.z;
    out_indf[b * NPP + t] = h.w;
  }
}

// ---------------- grouped MLP with FUSED ball query ----------------
// ballq block (b,s) maps 1:1 to mlp block (b,s): wave 0 does the scan
// (identical chunk order / f32 math / tie+tail handling as the former
// standalone kernel), then the block proceeds to gather+MLP. Scan latency
// of one block overlaps gather/FMA of other blocks on the CU.
__device__ __forceinline__ float4 bnrelu4(float4 a, float s, float b) {
  float4 r;
  r.x = fmaxf(fmaf(a.x, s, b), 0.f);
  r.y = fmaxf(fmaf(a.y, s, b), 0.f);
  r.z = fmaxf(fmaf(a.z, s, b), 0.f);
  r.w = fmaxf(fmaf(a.w, s, b), 0.f);
  return r;
}

__device__ __forceinline__ void layer4(const float (*in)[20], int cin,
                                       const float* __restrict__ WT,
                                       const float* __restrict__ sc,
                                       const float* __restrict__ bi,
                                       int o4, int k0,
                                       float4& r0, float4& r1,
                                       float4& r2, float4& r3) {
  float4 a0 = {0.f, 0.f, 0.f, 0.f}, a1 = a0, a2 = a0, a3 = a0;
  for (int c = 0; c < cin; ++c) {
    float4 w  = *(const float4*)(WT + c * 128 + o4);
    float4 gv = *(const float4*)(&in[c][k0]);
    a0.x = fmaf(w.x, gv.x, a0.x); a0.y = fmaf(w.x, gv.y, a0.y);
    a0.z = fmaf(w.x, gv.z, a0.z); a0.w = fmaf(w.x, gv.w, a0.w);
    a1.x = fmaf(w.y, gv.x, a1.x); a1.y = fmaf(w.y, gv.y, a1.y);
    a1.z = fmaf(w.y, gv.z, a1.z); a1.w = fmaf(w.y, gv.w, a1.w);
    a2.x = fmaf(w.z, gv.x, a2.x); a2.y = fmaf(w.z, gv.y, a2.y);
    a2.z = fmaf(w.z, gv.z, a2.z); a2.w = fmaf(w.z, gv.w, a2.w);
    a3.x = fmaf(w.w, gv.x, a3.x); a3.y = fmaf(w.w, gv.y, a3.y);
    a3.z = fmaf(w.w, gv.z, a3.z); a3.w = fmaf(w.w, gv.w, a3.w);
  }
  r0 = bnrelu4(a0, sc[o4 + 0], bi[o4 + 0]);
  r1 = bnrelu4(a1, sc[o4 + 1], bi[o4 + 1]);
  r2 = bnrelu4(a2, sc[o4 + 2], bi[o4 + 2]);
  r3 = bnrelu4(a3, sc[o4 + 3], bi[o4 + 3]);
}

__global__ __launch_bounds__(128) void mlp_kernel(
    const float* __restrict__ xyz, const float* __restrict__ feats,
    const float* __restrict__ centers,
    const float* __restrict__ W1T, const float* __restrict__ W2T,
    const float* __restrict__ W3T, const float* __restrict__ sa_sc,
    const float* __restrict__ sa_bi, float* __restrict__ feat0) {
  int bs = blockIdx.x;
  int b = bs >> 7;
  int s = bs & 127;
  int tid = threadIdx.x;
  __shared__ __align__(16) float g[259][20];   // 20720 B
  __shared__ __align__(16) float h1[128][20];  // 10240 B
  float (*h2)[20] = (float (*)[20]) & g[0][0]; // alias: g dead after layer1
  __shared__ int kidx[NSS];
  __shared__ int coll[NSS];
  __shared__ float ctr[3];
  const float* px = xyz + (size_t)b * (NN * 3);
  if (tid < 3) ctr[tid] = centers[bs * 3 + tid];
  if (tid < 64) {                        // wave 0: ball query scan
    int lane = tid;
    float cx = centers[bs * 3 + 0];
    float cy = centers[bs * 3 + 1];
    float cz = centers[bs * 3 + 2];
    const float rr = 0.09f;  // f32(0.09): identical membership to f64 cmp
    int have = 0;
    for (int c0 = 0; c0 < NN; c0 += 64) {
      int n = c0 + lane;
      float dx = __fsub_rn(px[n * 3 + 0], cx);
      float dy = __fsub_rn(px[n * 3 + 1], cy);
      float dz = __fsub_rn(px[n * 3 + 2], cz);
      float d2 = __fadd_rn(__fadd_rn(__fmul_rn(dx, dx), __fmul_rn(dy, dy)),
                           __fmul_rn(dz, dz));
      bool in = d2 < rr;
      unsigned long long m = __ballot(in);
      if (in) {
        int pos = have + __popcll(m & ((1ull << lane) - 1ull));
        if (pos < NSS) coll[pos] = n;
      }
      have += __popcll(m);
      if (have >= NSS) break;
    }
    int first = coll[0];
    if (lane < NSS) kidx[lane] = (lane < have) ? coll[lane] : first;
  }
  __syncthreads();
  if (tid < NSS) {
    int n = kidx[tid];
    g[0][tid] = __fdiv_rn(__fsub_rn(px[n * 3 + 0], ctr[0]), 0.3f);
    g[1][tid] = __fdiv_rn(__fsub_rn(px[n * 3 + 1], ctr[1]), 0.3f);
    g[2][tid] = __fdiv_rn(__fsub_rn(px[n * 3 + 2], ctr[2]), 0.3f);
  }
#pragma unroll
  for (int cc = 0; cc < 2; ++cc) {
    int c = tid + cc * 128;
    const float* row = feats + ((size_t)b * NC + c) * NN;
#pragma unroll
    for (int k = 0; k < NSS; ++k) g[3 + c][k] = row[kidx[k]];
  }
  __syncthreads();
  int o4 = (tid & 31) * 4;
  int k0 = (tid >> 5) * 4;   // 0,4,8,12
  float4 r0, r1, r2, r3;
  layer4(g, 259, W1T, sa_sc, sa_bi, o4, k0, r0, r1, r2, r3);
  *(float4*)&h1[o4 + 0][k0] = r0;
  *(float4*)&h1[o4 + 1][k0] = r1;
  *(float4*)&h1[o4 + 2][k0] = r2;
  *(float4*)&h1[o4 + 3][k0] = r3;
  __syncthreads();
  layer4(h1, 128, W2T, sa_sc + 128, sa_bi + 128, o4, k0, r0, r1, r2, r3);
  __syncthreads();                       // layer1's g reads done;
  *(float4*)&h2[o4 + 0][k0] = r0;        // safe to overwrite g as h2
  *(float4*)&h2[o4 + 1][k0] = r1;
  *(float4*)&h2[o4 + 2][k0] = r2;
  *(float4*)&h2[o4 + 3][k0] = r3;
  __syncthreads();
  layer4(h2, 128, W3T, sa_sc + 256, sa_bi + 256, o4, k0, r0, r1, r2, r3);
  float m0 = fmaxf(fmaxf(r0.x, r0.y), fmaxf(r0.z, r0.w));
  float m1 = fmaxf(fmaxf(r1.x, r1.y), fmaxf(r1.z, r1.w));
  float m2 = fmaxf(fmaxf(r2.x, r2.y), fmaxf(r2.z, r2.w));
  float m3 = fmaxf(fmaxf(r3.x, r3.y), fmaxf(r3.z, r3.w));
  int kg = tid >> 5;                     // h1 free (last read in layer2)
  h1[o4 + 0][kg] = m0;
  h1[o4 + 1][kg] = m1;
  h1[o4 + 2][kg] = m2;
  h1[o4 + 3][kg] = m3;
  __syncthreads();
  if (tid < 128) {
    float m = fmaxf(fmaxf(h1[tid][0], h1[tid][1]), fmaxf(h1[tid][2], h1[tid][3]));
    feat0[((size_t)b * 128 + tid) * 128 + s] = m;
  }
}

// ---------------- FC heads: (x@Wm + bm)*scale + bias, relu, x2 ----------------
__global__ __launch_bounds__(256) void head_kernel(
    const float* __restrict__ feat0, const float* __restrict__ WmT,
    const float* __restrict__ bm, const float* __restrict__ msc,
    const float* __restrict__ mbi, float* __restrict__ out_feat) {
  int blk = blockIdx.x;
  int b = blk >> 2;
  int sbase = (blk & 3) * 32;
  int tid = threadIdx.x;
  __shared__ float fa[128][36];
  __shared__ float fb[128][36];
  {
    int sj = tid & 31, c0 = tid >> 5;
    for (int c = c0; c < 128; c += 8)
      fa[c][sj] = feat0[((size_t)b * 128 + c) * 128 + sbase + sj];
  }
  __syncthreads();
  int o2 = (tid & 63) * 2, s0 = (tid >> 6) * 8;
  float a0[8], a1[8];
#pragma unroll
  for (int j = 0; j < 8; ++j) { a0[j] = 0.f; a1[j] = 0.f; }
  for (int c = 0; c < 128; ++c) {
    float2 w = *(const float2*)&WmT[c * 128 + o2];
    float4 f0 = *(const float4*)&fa[c][s0];
    float4 f1 = *(const float4*)&fa[c][s0 + 4];
    a0[0] = fmaf(w.x, f0.x, a0[0]); a0[1] = fmaf(w.x, f0.y, a0[1]);
    a0[2] = fmaf(w.x, f0.z, a0[2]); a0[3] = fmaf(w.x, f0.w, a0[3]);
    a0[4] = fmaf(w.x, f1.x, a0[4]); a0[5] = fmaf(w.x, f1.y, a0[5]);
    a0[6] = fmaf(w.x, f1.z, a0[6]); a0[7] = fmaf(w.x, f1.w, a0[7]);
    a1[0] = fmaf(w.y, f0.x, a1[0]); a1[1] = fmaf(w.y, f0.y, a1[1]);
    a1[2] = fmaf(w.y, f0.z, a1[2]); a1[3] = fmaf(w.y, f0.w, a1[3]);
    a1[4] = fmaf(w.y, f1.x, a1[4]); a1[5] = fmaf(w.y, f1.y, a1[5]);
    a1[6] = fmaf(w.y, f1.z, a1[6]); a1[7] = fmaf(w.y, f1.w, a1[7]);
  }
  {
    float c0 = bm[o2], c1 = bm[o2 + 1];
    float t0 = msc[o2], t1 = msc[o2 + 1];
    float q0 = mbi[o2], q1 = mbi[o2 + 1];
#pragma unroll
    for (int j = 0; j < 8; ++j) {
      fb[o2][s0 + j]     = fmaxf(fmaf(a0[j] + c0, t0, q0), 0.f);
      fb[o2 + 1][s0 + j] = fmaxf(fmaf(a1[j] + c1, t1, q1), 0.f);
    }
  }
  __syncthreads();
#pragma unroll
  for (int j = 0; j < 8; ++j) { a0[j] = 0.f; a1[j] = 0.f; }
  for (int c = 0; c < 128; ++c) {
    float2 w = *(const float2*)&WmT[16384 + c * 128 + o2];
    float4 f0 = *(const float4*)&fb[c][s0];
    float4 f1 = *(const float4*)&fb[c][s0 + 4];
    a0[0] = fmaf(w.x, f0.x, a0[0]); a0[1] = fmaf(w.x, f0.y, a0[1]);
    a0[2] = fmaf(w.x, f0.z, a0[2]); a0[3] = fmaf(w.x, f0.w, a0[3]);
    a0[4] = fmaf(w.x, f1.x, a0[4]); a0[5] = fmaf(w.x, f1.y, a0[5]);
    a0[6] = fmaf(w.x, f1.z, a0[6]); a0[7] = fmaf(w.x, f1.w, a0[7]);
    a1[0] = fmaf(w.y, f0.x, a1[0]); a1[1] = fmaf(w.y, f0.y, a1[1]);
    a1[2] = fmaf(w.y, f0.z, a1[2]); a1[3] = fmaf(w.y, f0.w, a1[3]);
    a1[4] = fmaf(w.y, f1.x, a1[4]); a1[5] = fmaf(w.y, f1.y, a1[5]);
    a1[6] = fmaf(w.y, f1.z, a1[6]); a1[7] = fmaf(w.y, f1.w, a1[7]);
  }
  {
    float c0 = bm[128 + o2], c1 = bm[128 + o2 + 1];
    float t0 = msc[128 + o2], t1 = msc[128 + o2 + 1];
    float q0 = mbi[128 + o2], q1 = mbi[128 + o2 + 1];
    float4 v0a, v0b, v1a, v1b;
    v0a.x = fmaxf(fmaf(a0[0] + c0, t0, q0), 0.f);
    v0a.y = fmaxf(fmaf(a0[1] + c0, t0, q0), 0.f);
    v0a.z = fmaxf(fmaf(a0[2] + c0, t0, q0), 0.f);
    v0a.w = fmaxf(fmaf(a0[3] + c0, t0, q0), 0.f);
    v0b.x = fmaxf(fmaf(a0[4] + c0, t0, q0), 0.f);
    v0b.y = fmaxf(fmaf(a0[5] + c0, t0, q0), 0.f);
    v0b.z = fmaxf(fmaf(a0[6] + c0, t0, q0), 0.f);
    v0b.w = fmaxf(fmaf(a0[7] + c0, t0, q0), 0.f);
    v1a.x = fmaxf(fmaf(a1[0] + c1, t1, q1), 0.f);
    v1a.y = fmaxf(fmaf(a1[1] + c1, t1, q1), 0.f);
    v1a.z = fmaxf(fmaf(a1[2] + c1, t1, q1), 0.f);
    v1a.w = fmaxf(fmaf(a1[3] + c1, t1, q1), 0.f);
    v1b.x = fmaxf(fmaf(a1[4] + c1, t1, q1), 0.f);
    v1b.y = fmaxf(fmaf(a1[5] + c1, t1, q1), 0.f);
    v1b.z = fmaxf(fmaf(a1[6] + c1, t1, q1), 0.f);
    v1b.w = fmaxf(fmaf(a1[7] + c1, t1, q1), 0.f);
    float* p0 = &out_feat[((size_t)b * 128 + o2) * 128 + sbase + s0];
    float* p1 = &out_feat[((size_t)b * 128 + o2 + 1) * 128 + sbase + s0];
    *(float4*)p0 = v0a;
    *(float4*)(p0 + 4) = v0b;
    *(float4*)p1 = v1a;
    *(float4*)(p1 + 4) = v1b;
  }
}

extern "C" void kernel_launch(void* const* d_in, const int* in_sizes, int n_in,
                              void* d_out, int out_size, void* d_ws, size_t ws_size,
                              hipStream_t stream) {
  const float* vote_xyz  = (const float*)d_in[0];
  const float* vote_feat = (const float*)d_in[1];
  const float* W1   = (const float*)d_in[2];
  const float* W2   = (const float*)d_in[3];
  const float* W3   = (const float*)d_in[4];
  const float* sasc = (const float*)d_in[5];
  const float* sabi = (const float*)d_in[6];
  const float* Wm   = (const float*)d_in[7];
  const float* bm   = (const float*)d_in[8];
  const float* msc  = (const float*)d_in[9];
  const float* mbi  = (const float*)d_in[10];

  float* out = (float*)d_out;
  float* out_xyz  = out;                    // B*NP*3   = 6144
  float* out_feat = out + 6144;             // B*128*NP = 262144
  float* out_indf = out + 6144 + 262144;    // B*NP     = 2048

  char* ws = (char*)d_ws;
  float* centers = (float*)(ws + 8192);     //  24 KB
  float* W1T     = (float*)(ws + 163840);   // 132608 B
  float* W2T     = (float*)(ws + 296448);   //  64 KB
  float* W3T     = (float*)(ws + 361984);   //  64 KB
  float* WmT     = (float*)(ws + 427520);   // 128 KB
  float* feat0   = (float*)(ws + 558592);   //   1 MB

  hipLaunchKernelGGL(transpose_kernel, dim3(130), dim3(256), 0, stream,
                     W1, W2, W3, Wm, W1T, W2T, W3T, WmT);
  hipLaunchKernelGGL(fps_kernel, dim3(NB), dim3(FTH), 0, stream,
                     vote_xyz, centers, out_xyz, out_indf);
  hipLaunchKernelGGL(mlp_kernel, dim3(NB * NPP), dim3(128), 0, stream,
                     vote_xyz, vote_feat, centers, W1T, W2T, W3T,
                     sasc, sabi, feat0);
  hipLaunchKernelGGL(head_kernel, dim3(NB * 4), dim3(256), 0, stream,
                     feat0, WmT, bm, msc, mbi, out_feat);
}